// Round 10
// baseline (155.004 us; speedup 1.0000x reference)
//
#include <hip/hip_runtime.h>
#include <hip/hip_bf16.h>
#include <stdint.h>

#define B_   512
#define C_   440
#define CR_  52
#define HW_  49
#define KP_  448          // padded K (=C) to multiple of 32 (= 7*64)
#define OP_  512          // padded O (=C) to multiple of 64 (8 o-tiles)
#define M_   25088        // B_*HW_ (= 392*64 exactly)
#define CCH_ 64           // c-chunk per scatter block
#define TSS_ 72           // scatter LDS row stride (shorts)
#define NT_  14           // K-steps (448/32)

typedef __attribute__((ext_vector_type(8))) short bf8;
typedef __attribute__((ext_vector_type(4))) float f4;

__device__ __forceinline__ unsigned short f2bf(float f) {
  union { float f; unsigned u; } v; v.f = f;
  unsigned r = v.u + 0x7FFFu + ((v.u >> 16) & 1u);
  return (unsigned short)(r >> 16);
}

__device__ __forceinline__ void gld16(const void* g, void* l) {
  __builtin_amdgcn_global_load_lds(
      (const __attribute__((address_space(1))) unsigned int*)g,
      (__attribute__((address_space(3))) unsigned int*)l, 16, 0, 0);
}

// ------- K1: w3 fp32 -> bf16 padded [OP_][KP_]; block 0 zeroes gstats -------
__global__ __launch_bounds__(256) void k_prep_w3(const float* __restrict__ w3,
                                                 unsigned short* __restrict__ w3bf,
                                                 float* __restrict__ gstats) {
  int idx = blockIdx.x * 256 + threadIdx.x;      // grid covers 512*448 exactly
  if (blockIdx.x == 0) {
    #pragma unroll
    for (int i = 0; i < 4; ++i) gstats[threadIdx.x + i * 256] = 0.f;  // 2*OP_ floats
  }
  int o = idx / KP_, c = idx - o * KP_;
  float v = (c < C_ && o < C_) ? w3[o * C_ + c] : 0.f;
  w3bf[idx] = f2bf(v);
}

// ---------------- K2a: per-b gate MLP -> gate[b][c] fp32 ----------------
__global__ __launch_bounds__(256) void k_gate(
    const float* __restrict__ x178,
    const float* __restrict__ w1, const float* __restrict__ b1,
    const float* __restrict__ w2, const float* __restrict__ b2,
    float* __restrict__ gate) {
  __shared__ __align__(16) float s_s[C_];
  __shared__ __align__(16) float s_h[CR_ + 12];   // padded to 64 floats (16 f4)
  int b = blockIdx.x, tid = threadIdx.x;

  if (tid < C_ / 4) ((f4*)s_s)[tid] = ((const f4*)(x178 + (size_t)b * C_))[tid];
  if (tid >= 240 && tid < 240 + 16) ((f4*)s_h)[tid - 240] = f4{0.f, 0.f, 0.f, 0.f};
  __syncthreads();

  int r = tid >> 2, q = tid & 3;     // 64 rows x 4 threads (rows 52..63 idle)
  if (r < CR_) {
    const f4* wr = (const f4*)(w1 + (size_t)r * C_);   // 110 f4 per row
    const f4* ss = (const f4*)s_s;
    f4 acc = {0.f, 0.f, 0.f, 0.f};
    #pragma unroll
    for (int j0 = 0; j0 < 28; ++j0) {
      int j = q + j0 * 4;
      if (j < C_ / 4) {
        f4 w = wr[j], x = ss[j];
        acc += w * x;
      }
    }
    float a = acc[0] + acc[1] + acc[2] + acc[3];
    a += __shfl_xor(a, 1, 64);
    a += __shfl_xor(a, 2, 64);
    if (q == 0) s_h[r] = fmaxf(a + b1[r], 0.f);
  }
  __syncthreads();

  for (int c = tid; c < C_; c += 256) {
    const f4* wc = (const f4*)(w2 + (size_t)c * CR_);  // 13 f4 per row
    const f4* hh = (const f4*)s_h;
    f4 acc = {0.f, 0.f, 0.f, 0.f};
    #pragma unroll
    for (int j = 0; j < 13; ++j) acc += wc[j] * hh[j];
    float a = acc[0] + acc[1] + acc[2] + acc[3] + b2[c];
    gate[b * C_ + c] = 1.f / (1.f + __expf(-a));
  }
}

// ------- K2b: gating + bf16 + transpose, one block per (c-chunk, b) -------
__global__ __launch_bounds__(256) void k_scatter(
    const float* __restrict__ x177, const float* __restrict__ gate,
    unsigned short* __restrict__ gbf) {
  __shared__ __align__(16) unsigned short s_t[HW_ * TSS_];  // [49][72] bf16
  __shared__ float s_g[CCH_];
  int cc = blockIdx.x, b = blockIdx.y, tid = threadIdx.x;
  int c0 = cc * CCH_;
  int valid_c = (c0 + CCH_ <= C_) ? CCH_ : (C_ - c0);   // 64 or 56 (chunk 6)

  unsigned* zt = (unsigned*)s_t;
  for (int i = tid; i < HW_ * TSS_ / 2; i += 256) zt[i] = 0u;
  if (tid < CCH_) {
    int c = c0 + tid;
    s_g[tid] = (c < C_) ? gate[b * C_ + c] : 0.f;
  }
  __syncthreads();

  const f4* xp = (const f4*)(x177 + (size_t)b * (C_ * HW_) + (size_t)c0 * HW_);
  int nvec = valid_c * HW_ / 4;   // 784 or 686 (both exact)
  for (int it = 0; it < 4; ++it) {
    int idx = it * 256 + tid;
    if (idx < nvec) {
      f4 v = xp[idx];
      int e = idx * 4;
      #pragma unroll
      for (int j = 0; j < 4; ++j) {
        int ej = e + j;
        int cl = ej / HW_, hw = ej - cl * HW_;
        s_t[hw * TSS_ + cl] = f2bf(v[j] * s_g[cl]);
      }
    }
  }
  __syncthreads();

  unsigned short* gp = gbf + (size_t)b * HW_ * KP_ + c0;
  for (int it = 0; it < 2; ++it) {
    int p = it * 256 + tid;
    if (p < HW_ * (CCH_ / 8)) {
      int hw = p >> 3, cg = p & 7;
      *(bf8*)(gp + hw * KP_ + cg * 8) = *(const bf8*)(s_t + hw * TSS_ + cg * 8);
    }
  }
}

// ---- K3: 1-wave 64x64 tiles, fenced 2-slot counted-vmcnt pipeline ----
// grid 3136 = 8 XCD-chunks x 49 m-groups x 8 o-tiles
__global__ __launch_bounds__(64, 2) void k_gemm(const unsigned short* __restrict__ w3bf,
                                                const unsigned short* __restrict__ gbf,
                                                float* __restrict__ y,
                                                float* __restrict__ gstats) {
  __shared__ __align__(16) unsigned short lds[2 * 4096];   // 2 slots x (A 4KB | B 4KB)
  int lane = threadIdx.x;                    // one wave per block
  // XCD-chunked bijective swizzle: XCD x owns m-tiles [49x, 49x+49), all 8 o
  int i0 = blockIdx.x;
  int x = i0 & 7, jj0 = i0 >> 3;
  int ot = jj0 & 7, mt = x * 49 + (jj0 >> 3);
  int o0 = ot * 64, m0 = mt * 64;
  const char* Ab = (const char*)w3bf;  // row stride 896 B
  const char* Bb = (const char*)gbf;   // row stride 896 B
  f4 acc[4][4] = {};

  // staging: lane l writes LDS linearly (row l>>2, 16B-chunk l&3);
  // source chunk pre-XOR'd by (row>>1)&3 (bank de-conflict; both-sides swizzle)
  int sr = lane >> 2;
  int scc = ((lane & 3) ^ ((sr >> 1) & 3)) * 16;
  auto stage = [&](int slot, int kt) {
    int k0b = kt * 64;
    char* lb = (char*)lds + slot * 8192;
    #pragma unroll
    for (int i = 0; i < 4; ++i) {
      gld16(Ab + (size_t)(o0 + i * 16 + sr) * 896 + k0b + scc, lb + i * 1024);
      gld16(Bb + (size_t)(m0 + i * 16 + sr) * 896 + k0b + scc, lb + 4096 + i * 1024);
    }
  };

  stage(0, 0);
  stage(1, 1);     // 16 loads outstanding

  int rl = lane & 15;
  int ch = (((lane >> 4) ^ ((rl >> 1) & 3)) << 3);   // swizzled read chunk (shorts)
  for (int kt = 0; kt < NT_; ++kt) {
    int cur = kt & 1;
    // stage(kt) landed (8 newest = stage(kt+1) may stay in flight)
    if (kt + 1 < NT_) asm volatile("s_waitcnt vmcnt(8)" ::: "memory");
    else              asm volatile("s_waitcnt vmcnt(0)" ::: "memory");

    const unsigned short* base = lds + cur * 4096;
    bf8 a[4], bb[4];
    #pragma unroll
    for (int i = 0; i < 4; ++i) a[i]  = *(const bf8*)(base + (i * 16 + rl) * 32 + ch);
    #pragma unroll
    for (int i = 0; i < 4; ++i) bb[i] = *(const bf8*)(base + 2048 + (i * 16 + rl) * 32 + ch);

    // WAR fence: ds_reads COMPLETE (lgkm pipe) before gld16 overwrites this
    // slot (vm-pipe LDS write-back has no cross-pipe ordering vs ds_read).
    asm volatile("s_waitcnt lgkmcnt(0)" ::: "memory");
    __builtin_amdgcn_sched_barrier(0);
    if (kt + 2 < NT_) stage(cur, kt + 2);    // refill just-read slot
    __builtin_amdgcn_sched_barrier(0);       // keep MFMAs below stage issue

    #pragma unroll
    for (int i = 0; i < 4; ++i)
      #pragma unroll
      for (int j = 0; j < 4; ++j)
        acc[i][j] = __builtin_amdgcn_mfma_f32_16x16x32_bf16(a[i], bb[j], acc[i][j], 0, 0, 0);
  }

  // D layout: col = lane&15 (m), row = (lane>>4)*4 + reg (o)
  int col = rl, r4 = (lane >> 4) * 4;
  #pragma unroll
  for (int i = 0; i < 4; ++i) {
    int ob = o0 + i * 16 + r4;
    #pragma unroll
    for (int j = 0; j < 4; ++j) {
      int m = m0 + j * 16 + col;
      #pragma unroll
      for (int r = 0; r < 4; ++r) {
        int o = ob + r;
        if (o < C_) y[(size_t)o * M_ + m] = acc[i][j][r];
      }
    }
  }

  // fused stats: row-sums over this block's 64 m-cols, then atomics
  #pragma unroll
  for (int i = 0; i < 4; ++i) {
    float s[4], q[4];
    #pragma unroll
    for (int r = 0; r < 4; ++r) {
      float ss = 0.f, qq = 0.f;
      #pragma unroll
      for (int j = 0; j < 4; ++j) { float v = acc[i][j][r]; ss += v; qq += v * v; }
      s[r] = ss; q[r] = qq;
    }
    #pragma unroll
    for (int off = 1; off < 16; off <<= 1) {
      #pragma unroll
      for (int r = 0; r < 4; ++r) {
        s[r] += __shfl_xor(s[r], off, 64);
        q[r] += __shfl_xor(q[r], off, 64);
      }
    }
    if (rl == 0) {
      int row = o0 + i * 16 + r4;
      #pragma unroll
      for (int r = 0; r < 4; ++r) {
        int o = row + r;
        if (o < C_) {
          atomicAdd(&gstats[o * 2 + 0], s[r]);
          atomicAdd(&gstats[o * 2 + 1], q[r]);
        }
      }
    }
  }
}

// -------- K4: single-pass normalize y -> out using fused gstats --------
__global__ __launch_bounds__(256) void k_norm(const float* __restrict__ y,
                                              const float* __restrict__ gstats,
                                              const float* __restrict__ gamma,
                                              const float* __restrict__ beta,
                                              float* __restrict__ out) {
  int o = blockIdx.x, seg = blockIdx.y, tid = threadIdx.x;
  float S = gstats[o * 2 + 0], Q = gstats[o * 2 + 1];
  float mean = S * (1.f / (float)M_);
  float var  = Q * (1.f / (float)M_) - mean * mean;
  float sc = gamma[o] * rsqrtf(var + 1e-5f);
  float sh = beta[o] - mean * sc;
  const f4* yr = (const f4*)(y + (size_t)o * M_ + (size_t)seg * (M_ / 4));
  for (int i = tid; i < M_ / 16; i += 256) {       // 1568 f4 per segment
    f4 v = yr[i];
    int m = seg * (M_ / 4) + i * 4;
    #pragma unroll
    for (int j = 0; j < 4; ++j) {
      int mm = m + j;
      int bb = mm / HW_, hw = mm - bb * HW_;
      out[(size_t)bb * (C_ * HW_) + o * HW_ + hw] = v[j] * sc + sh;
    }
  }
}

extern "C" void kernel_launch(void* const* d_in, const int* in_sizes, int n_in,
                              void* d_out, int out_size, void* d_ws, size_t ws_size,
                              hipStream_t stream) {
  const float* x178 = (const float*)d_in[0];
  const float* x177 = (const float*)d_in[1];
  const float* w1   = (const float*)d_in[2];
  const float* b1   = (const float*)d_in[3];
  const float* w2   = (const float*)d_in[4];
  const float* b2   = (const float*)d_in[5];
  const float* w3   = (const float*)d_in[6];
  const float* gamma= (const float*)d_in[7];
  const float* beta = (const float*)d_in[8];
  float* out = (float*)d_out;

  char* ws = (char*)d_ws;
  unsigned short* w3bf = (unsigned short*)ws;                        // 512*448*2 = 458752
  unsigned short* gbf  = (unsigned short*)(ws + 458752);             // 25088*448*2 = 22478848
  float* y             = (float*)(ws + 458752 + 22478848);           // 440*25088*4 = 44154880
  float* gstats        = (float*)(ws + 458752 + 22478848 + 44154880); // 2*512*4 = 4096
  float* gate          = y;   // head of y region; consumed before k_gemm writes y

  hipLaunchKernelGGL(k_prep_w3, dim3((OP_ * KP_) / 256), dim3(256), 0, stream,
                     w3, w3bf, gstats);
  hipLaunchKernelGGL(k_gate, dim3(B_), dim3(256), 0, stream,
                     x178, w1, b1, w2, b2, gate);
  hipLaunchKernelGGL(k_scatter, dim3(KP_ / CCH_, B_), dim3(256), 0, stream,
                     x177, gate, gbf);
  hipLaunchKernelGGL(k_gemm, dim3((M_ / 64) * (OP_ / 64)), dim3(64), 0, stream,
                     w3bf, gbf, y, gstats);
  hipLaunchKernelGGL(k_norm, dim3(C_, 4), dim3(256), 0, stream,
                     y, gstats, gamma, beta, out);
}

// Round 11
// 90.693 us; speedup vs baseline: 1.7091x; 1.7091x over previous
//
#include <hip/hip_runtime.h>
#include <hip/hip_bf16.h>
#include <stdint.h>

#define B_   512
#define C_   440
#define CR_  52
#define HW_  49
#define KP_  448          // padded K (=C) to multiple of 64 (= 7*64)
#define OP_  512          // padded O (=C): 4 o-tiles of 128
#define M_   25088        // B_*HW_ (= 196*128 exactly)
#define CCH_ 64           // c-chunk per scatter block
#define TSS_ 72           // scatter LDS row stride (shorts)
#define NKT_ 7            // K-steps (448/64), BK=64

typedef __attribute__((ext_vector_type(8))) short bf8;
typedef __attribute__((ext_vector_type(4))) float f4;

__device__ __forceinline__ unsigned short f2bf(float f) {
  union { float f; unsigned u; } v; v.f = f;
  unsigned r = v.u + 0x7FFFu + ((v.u >> 16) & 1u);
  return (unsigned short)(r >> 16);
}
__device__ __forceinline__ float bf2f(unsigned short u) {
  union { unsigned u; float f; } v; v.u = ((unsigned)u) << 16; return v.f;
}

__device__ __forceinline__ void gld16(const void* g, void* l) {
  __builtin_amdgcn_global_load_lds(
      (const __attribute__((address_space(1))) unsigned int*)g,
      (__attribute__((address_space(3))) unsigned int*)l, 16, 0, 0);
}

// ------- K1: w3 fp32 -> bf16 padded [OP_][KP_]; block 0 zeroes gstats -------
__global__ __launch_bounds__(256) void k_prep_w3(const float* __restrict__ w3,
                                                 unsigned short* __restrict__ w3bf,
                                                 float* __restrict__ gstats) {
  int idx = blockIdx.x * 256 + threadIdx.x;      // grid covers 512*448 exactly
  if (blockIdx.x == 0) {
    #pragma unroll
    for (int i = 0; i < 4; ++i) gstats[threadIdx.x + i * 256] = 0.f;  // 2*OP_ floats
  }
  int o = idx / KP_, c = idx - o * KP_;
  float v = (c < C_ && o < C_) ? w3[o * C_ + c] : 0.f;
  w3bf[idx] = f2bf(v);
}

// ---------------- K2a: per-b gate MLP -> gate[b][c] fp32 ----------------
__global__ __launch_bounds__(256) void k_gate(
    const float* __restrict__ x178,
    const float* __restrict__ w1, const float* __restrict__ b1,
    const float* __restrict__ w2, const float* __restrict__ b2,
    float* __restrict__ gate) {
  __shared__ __align__(16) float s_s[C_];
  __shared__ __align__(16) float s_h[CR_ + 12];   // padded to 64 floats (16 f4)
  int b = blockIdx.x, tid = threadIdx.x;

  if (tid < C_ / 4) ((f4*)s_s)[tid] = ((const f4*)(x178 + (size_t)b * C_))[tid];
  if (tid >= 240 && tid < 240 + 16) ((f4*)s_h)[tid - 240] = f4{0.f, 0.f, 0.f, 0.f};
  __syncthreads();

  int r = tid >> 2, q = tid & 3;     // 64 rows x 4 threads (rows 52..63 idle)
  if (r < CR_) {
    const f4* wr = (const f4*)(w1 + (size_t)r * C_);   // 110 f4 per row
    const f4* ss = (const f4*)s_s;
    f4 acc = {0.f, 0.f, 0.f, 0.f};
    #pragma unroll
    for (int j0 = 0; j0 < 28; ++j0) {
      int j = q + j0 * 4;
      if (j < C_ / 4) {
        f4 w = wr[j], x = ss[j];
        acc += w * x;
      }
    }
    float a = acc[0] + acc[1] + acc[2] + acc[3];
    a += __shfl_xor(a, 1, 64);
    a += __shfl_xor(a, 2, 64);
    if (q == 0) s_h[r] = fmaxf(a + b1[r], 0.f);
  }
  __syncthreads();

  for (int c = tid; c < C_; c += 256) {
    const f4* wc = (const f4*)(w2 + (size_t)c * CR_);  // 13 f4 per row
    const f4* hh = (const f4*)s_h;
    f4 acc = {0.f, 0.f, 0.f, 0.f};
    #pragma unroll
    for (int j = 0; j < 13; ++j) acc += wc[j] * hh[j];
    float a = acc[0] + acc[1] + acc[2] + acc[3] + b2[c];
    gate[b * C_ + c] = 1.f / (1.f + __expf(-a));
  }
}

// ------- K2b: gating + bf16 + transpose, one block per (c-chunk, b) -------
__global__ __launch_bounds__(256) void k_scatter(
    const float* __restrict__ x177, const float* __restrict__ gate,
    unsigned short* __restrict__ gbf) {
  __shared__ __align__(16) unsigned short s_t[HW_ * TSS_];  // [49][72] bf16
  __shared__ float s_g[CCH_];
  int cc = blockIdx.x, b = blockIdx.y, tid = threadIdx.x;
  int c0 = cc * CCH_;
  int valid_c = (c0 + CCH_ <= C_) ? CCH_ : (C_ - c0);   // 64 or 56 (chunk 6)

  unsigned* zt = (unsigned*)s_t;
  for (int i = tid; i < HW_ * TSS_ / 2; i += 256) zt[i] = 0u;
  if (tid < CCH_) {
    int c = c0 + tid;
    s_g[tid] = (c < C_) ? gate[b * C_ + c] : 0.f;
  }
  __syncthreads();

  const f4* xp = (const f4*)(x177 + (size_t)b * (C_ * HW_) + (size_t)c0 * HW_);
  int nvec = valid_c * HW_ / 4;   // 784 or 686 (both exact)
  for (int it = 0; it < 4; ++it) {
    int idx = it * 256 + tid;
    if (idx < nvec) {
      f4 v = xp[idx];
      int e = idx * 4;
      #pragma unroll
      for (int j = 0; j < 4; ++j) {
        int ej = e + j;
        int cl = ej / HW_, hw = ej - cl * HW_;
        s_t[hw * TSS_ + cl] = f2bf(v[j] * s_g[cl]);
      }
    }
  }
  __syncthreads();

  unsigned short* gp = gbf + (size_t)b * HW_ * KP_ + c0;
  for (int it = 0; it < 2; ++it) {
    int p = it * 256 + tid;
    if (p < HW_ * (CCH_ / 8)) {
      int hw = p >> 3, cg = p & 7;
      *(bf8*)(gp + hw * KP_ + cg * 8) = *(const bf8*)(s_t + hw * TSS_ + cg * 8);
    }
  }
}

// ---- K3: y[o][m] (bf16) = sum_c w3[o][c]*g[m][c]; BK=64, 2-phase dbuf ----
// 7 K-steps, 32 MFMA/iter/wave, 64 KB LDS, both-sides 8-chunk XOR swizzle.
__global__ __launch_bounds__(256, 2) void k_gemm(const unsigned short* __restrict__ w3bf,
                                                 const unsigned short* __restrict__ gbf,
                                                 unsigned short* __restrict__ ybf,
                                                 float* __restrict__ gstats) {
  // buf: [A 128x64 | B 128x64] bf16 = 32 KB; x2 dbuf = 64 KB
  __shared__ __align__(16) unsigned short lds[2 * 16384];
  int tid = threadIdx.x, lane = tid & 63, wv = tid >> 6;
  // XCD-aware bijective chunked swizzle (784 = 8 * 98)
  int bid0 = blockIdx.x;
  int bid = (bid0 & 7) * 98 + (bid0 >> 3);
  int o0 = (bid & 3) * 128;        // 4 o-tiles
  int m0 = (bid >> 2) * 128;       // 196 m-tiles
  int wr = wv >> 1, wc = wv & 1;
  f4 acc[4][4] = {};
  const char* Ab = (const char*)w3bf;  // row stride 896 B
  const char* Bb = (const char*)gbf;   // row stride 896 B

  // staging: unit u = i*4+wv covers rows u*8..u*8+7 (8 chunks of 16B per row).
  // LDS linear (gld16 contract); global chunk pre-XOR'd by row&7 (=lane>>3).
  int rowl = lane >> 3;                       // 0..7
  int crg  = (lane & 7) ^ rowl;               // source chunk (both-sides swz)
  auto stage = [&](int buf, int kt) {
    char* lb = (char*)lds + buf * 32768;
    int k0b = kt * 128;
    #pragma unroll
    for (int i = 0; i < 4; ++i) {
      int u = i * 4 + wv;
      int row = u * 8 + rowl;
      gld16(Ab + (size_t)(o0 + row) * 896 + k0b + crg * 16, lb + u * 1024);
      gld16(Bb + (size_t)(m0 + row) * 896 + k0b + crg * 16, lb + 16384 + u * 1024);
    }
  };

  stage(0, 0);
  asm volatile("s_waitcnt vmcnt(0)" ::: "memory");
  __builtin_amdgcn_s_barrier();

  int rl = lane & 15, l16q = lane >> 4;
  for (int kt = 0; kt < NKT_; ++kt) {
    int cur = kt & 1;
    if (kt + 1 < NKT_) stage(cur ^ 1, kt + 1);   // prefetch under compute

    const char* base = (const char*)lds + cur * 32768;
    bf8 a[4][2], bb[4][2];
    #pragma unroll
    for (int i = 0; i < 4; ++i) {
      int row = wr * 64 + i * 16 + rl;
      #pragma unroll
      for (int g = 0; g < 2; ++g)
        a[i][g] = *(const bf8*)(base + row * 128 + (((g * 4 + l16q) ^ (rl & 7)) * 16));
    }
    #pragma unroll
    for (int j = 0; j < 4; ++j) {
      int row = wc * 64 + j * 16 + rl;
      #pragma unroll
      for (int g = 0; g < 2; ++g)
        bb[j][g] = *(const bf8*)(base + 16384 + row * 128 + (((g * 4 + l16q) ^ (rl & 7)) * 16));
    }
    #pragma unroll
    for (int g = 0; g < 2; ++g)
      #pragma unroll
      for (int i = 0; i < 4; ++i)
        #pragma unroll
        for (int j = 0; j < 4; ++j)
          acc[i][j] = __builtin_amdgcn_mfma_f32_16x16x32_bf16(a[i][g], bb[j][g], acc[i][j], 0, 0, 0);

    if (kt + 1 < NKT_) {
      asm volatile("s_waitcnt vmcnt(0)" ::: "memory");  // next tile landed
      __builtin_amdgcn_s_barrier();
    }
  }

  // D layout: col = lane&15 (m), row = (lane>>4)*4 + reg (o); store bf16
  int col = rl, r4 = l16q * 4;
  #pragma unroll
  for (int i = 0; i < 4; ++i) {
    int ob = o0 + wr * 64 + i * 16 + r4;
    #pragma unroll
    for (int j = 0; j < 4; ++j) {
      int m = m0 + wc * 64 + j * 16 + col;
      #pragma unroll
      for (int r = 0; r < 4; ++r) {
        int o = ob + r;
        if (o < C_) ybf[(size_t)o * M_ + m] = f2bf(acc[i][j][r]);
      }
    }
  }

  // fused stats (fp32 acc): per-block sum/sumsq over 128 m-cols
  __syncthreads();
  float* part = (float*)lds;            // [128 rows][2 wc][2 {sum,sq}] = 2 KB
  #pragma unroll
  for (int i = 0; i < 4; ++i) {
    float s[4], q[4];
    #pragma unroll
    for (int r = 0; r < 4; ++r) {
      float ss = 0.f, qq = 0.f;
      #pragma unroll
      for (int j = 0; j < 4; ++j) { float v = acc[i][j][r]; ss += v; qq += v * v; }
      s[r] = ss; q[r] = qq;
    }
    #pragma unroll
    for (int off = 1; off < 16; off <<= 1) {
      #pragma unroll
      for (int r = 0; r < 4; ++r) {
        s[r] += __shfl_xor(s[r], off, 64);
        q[r] += __shfl_xor(q[r], off, 64);
      }
    }
    if (rl == 0) {
      int row = wr * 64 + i * 16 + r4;
      #pragma unroll
      for (int r = 0; r < 4; ++r) {
        part[(row + r) * 4 + wc * 2 + 0] = s[r];
        part[(row + r) * 4 + wc * 2 + 1] = q[r];
      }
    }
  }
  __syncthreads();
  {
    int row = tid >> 1, which = tid & 1;          // 256 threads = 128 rows x 2
    float v = part[row * 4 + which] + part[row * 4 + 2 + which];
    int o = o0 + row;
    if (o < C_) atomicAdd(&gstats[o * 2 + which], v);
  }
}

// -------- K4: single-pass normalize bf16 y -> fp32 out using gstats --------
__global__ __launch_bounds__(256) void k_norm(const unsigned short* __restrict__ ybf,
                                              const float* __restrict__ gstats,
                                              const float* __restrict__ gamma,
                                              const float* __restrict__ beta,
                                              float* __restrict__ out) {
  int o = blockIdx.x, seg = blockIdx.y, tid = threadIdx.x;
  float S = gstats[o * 2 + 0], Q = gstats[o * 2 + 1];
  float mean = S * (1.f / (float)M_);
  float var  = Q * (1.f / (float)M_) - mean * mean;
  float sc = gamma[o] * rsqrtf(var + 1e-5f);
  float sh = beta[o] - mean * sc;
  const bf8* yr = (const bf8*)(ybf + (size_t)o * M_ + (size_t)seg * (M_ / 4));
  for (int i = tid; i < M_ / 32; i += 256) {       // 784 bf8 per segment
    bf8 v = yr[i];
    int m = seg * (M_ / 4) + i * 8;
    #pragma unroll
    for (int j = 0; j < 8; ++j) {
      int mm = m + j;
      int bb = mm / HW_, hw = mm - bb * HW_;
      out[(size_t)bb * (C_ * HW_) + o * HW_ + hw] =
          bf2f((unsigned short)v[j]) * sc + sh;
    }
  }
}

extern "C" void kernel_launch(void* const* d_in, const int* in_sizes, int n_in,
                              void* d_out, int out_size, void* d_ws, size_t ws_size,
                              hipStream_t stream) {
  const float* x178 = (const float*)d_in[0];
  const float* x177 = (const float*)d_in[1];
  const float* w1   = (const float*)d_in[2];
  const float* b1   = (const float*)d_in[3];
  const float* w2   = (const float*)d_in[4];
  const float* b2   = (const float*)d_in[5];
  const float* w3   = (const float*)d_in[6];
  const float* gamma= (const float*)d_in[7];
  const float* beta = (const float*)d_in[8];
  float* out = (float*)d_out;

  char* ws = (char*)d_ws;
  unsigned short* w3bf = (unsigned short*)ws;                        // 512*448*2 = 458752
  unsigned short* gbf  = (unsigned short*)(ws + 458752);             // 25088*448*2 = 22478848
  unsigned short* ybf  = (unsigned short*)(ws + 458752 + 22478848);  // 440*25088*2 (region reserves 44MB)
  float* gstats        = (float*)(ws + 458752 + 22478848 + 44154880); // same offset as before
  float* gate          = (float*)ybf;  // head of y region; consumed before k_gemm writes ybf

  hipLaunchKernelGGL(k_prep_w3, dim3((OP_ * KP_) / 256), dim3(256), 0, stream,
                     w3, w3bf, gstats);
  hipLaunchKernelGGL(k_gate, dim3(B_), dim3(256), 0, stream,
                     x178, w1, b1, w2, b2, gate);
  hipLaunchKernelGGL(k_scatter, dim3(KP_ / CCH_, B_), dim3(256), 0, stream,
                     x177, gate, gbf);
  hipLaunchKernelGGL(k_gemm, dim3((M_ / 128) * (OP_ / 128)), dim3(256), 0, stream,
                     w3bf, gbf, ybf, gstats);
  hipLaunchKernelGGL(k_norm, dim3(C_, 4), dim3(256), 0, stream,
                     ybf, gstats, gamma, beta, out);
}